// Round 1
// baseline (349.374 us; speedup 1.0000x reference)
//
#include <hip/hip_runtime.h>

// Problem dims
#define MDIM 4096
#define KDIM 2048
#define HDIM 2048

using bf16x8 = __attribute__((ext_vector_type(8))) short;   // 8 bf16 = 4 VGPRs (per guide §3)
using f32x4  = __attribute__((ext_vector_type(4))) float;   // MFMA 16x16 accumulator

// ---------- fp32 -> bf16 (RNE) conversion ----------
__device__ __forceinline__ unsigned short f2bf(float f) {
  unsigned u = __float_as_uint(f);
  u += 0x7fffu + ((u >> 16) & 1u);           // round-to-nearest-even
  return (unsigned short)(u >> 16);
}

__global__ void cvt_x(const float* __restrict__ s, unsigned short* __restrict__ d, int n4) {
  int i = blockIdx.x * blockDim.x + threadIdx.x;
  int stride = gridDim.x * blockDim.x;
  const float4* s4 = (const float4*)s;
  ushort4* d4 = (ushort4*)d;
  for (int j = i; j < n4; j += stride) {
    float4 v = s4[j];
    ushort4 o;
    o.x = f2bf(v.x); o.y = f2bf(v.y); o.z = f2bf(v.z); o.w = f2bf(v.w);
    d4[j] = o;
  }
}

// blockIdx.y selects which W; dst is [4][H][K] bf16 gate-major
__global__ void cvt_w(const float* __restrict__ w0, const float* __restrict__ w1,
                      const float* __restrict__ w2, const float* __restrict__ w3,
                      unsigned short* __restrict__ d) {
  const float* src = (blockIdx.y == 0) ? w0 : (blockIdx.y == 1) ? w1 : (blockIdx.y == 2) ? w2 : w3;
  unsigned short* dst = d + (size_t)blockIdx.y * ((size_t)HDIM * KDIM);
  const int n4 = (HDIM * KDIM) / 4;
  int i = blockIdx.x * blockDim.x + threadIdx.x;
  int stride = gridDim.x * blockDim.x;
  const float4* s4 = (const float4*)src;
  ushort4* d4 = (ushort4*)dst;
  for (int j = i; j < n4; j += stride) {
    float4 v = s4[j];
    ushort4 o;
    o.x = f2bf(v.x); o.y = f2bf(v.y); o.z = f2bf(v.z); o.w = f2bf(v.w);
    d4[j] = o;
  }
}

// ---------- async global -> LDS (16B per lane) ----------
__device__ __forceinline__ void g2l16(const unsigned short* g, unsigned short* l) {
  __builtin_amdgcn_global_load_lds(
      (const __attribute__((address_space(1))) void*)g,
      (__attribute__((address_space(3))) void*)l, 16, 0, 0);
}

// ---------- fast activations (tolerance is 1.19e-2; __expf is plenty) ----------
__device__ __forceinline__ float fast_sigmoid(float x) {
  return __builtin_amdgcn_rcpf(1.f + __expf(-x));
}
__device__ __forceinline__ float fast_tanh(float x) {
  x = fminf(15.f, fmaxf(-15.f, x));          // keep __expf finite
  float e = __expf(2.f * x);
  return (e - 1.f) * __builtin_amdgcn_rcpf(e + 1.f);
}

// ---------- fused 4-gate GEMM + LSTM epilogue ----------
// Block tile: 128 M x 32 H x 4 gates (effective 128x128 GEMM tile), BK=64.
// 4 waves split M (wave w -> rows w*32..w*32+31). Each wave: 2 m-frags x 2 n-frags x 4 gates
// = 16 f32x4 accumulators. Epilogue: all 4 gates of a given (m,h) are in the same lane/reg.
__global__ __launch_bounds__(256) void lstm_fused(
    const unsigned short* __restrict__ xb,   // [M][K] bf16
    const unsigned short* __restrict__ wb,   // [4][H][K] bf16
    const float* __restrict__ b0, const float* __restrict__ b1,
    const float* __restrict__ b2, const float* __restrict__ b3,
    const float* __restrict__ cxp,           // [H]
    float* __restrict__ out)                 // [M][H] fp32
{
  // Unpadded row-major (global_load_lds requires lane-contiguous LDS dest)
  __shared__ __align__(16) unsigned short As[128 * 64];      // 16 KB
  __shared__ __align__(16) unsigned short Bs[4 * 32 * 64];   // 16 KB

  const int t    = threadIdx.x;
  const int lane = t & 63;
  const int wave = t >> 6;
  const int r    = lane & 15;   // MFMA row/col within frag
  const int q    = lane >> 4;   // quad

  const int m0 = blockIdx.y * 128;
  const int h0 = blockIdx.x * 32;

  f32x4 acc[4][2][2] = {};      // [gate][mf][nf]

  const unsigned short* xg = xb + (size_t)m0 * KDIM;
  const int brow = t >> 3;            // B staging: row 0..31
  const int bk8  = (t & 7) * 8;       // B staging: k-chunk

  for (int k0 = 0; k0 < KDIM; k0 += 64) {
    __syncthreads();                   // previous tile's compute done
    // Stage A: 128x64 bf16 = 16KB = 4 calls x 256 threads x 16B
#pragma unroll
    for (int c = 0; c < 4; ++c) {
      int idx = c * 256 + t;           // chunk index; 8 chunks per row
      g2l16(xg + (size_t)(idx >> 3) * KDIM + k0 + (idx & 7) * 8, As + idx * 8);
    }
    // Stage B: 4 gates x 32x64 bf16 = 16KB; call g stages gate g's slab
#pragma unroll
    for (int g = 0; g < 4; ++g) {
      g2l16(wb + (size_t)g * HDIM * KDIM + (size_t)(h0 + brow) * KDIM + k0 + bk8,
            Bs + g * 2048 + t * 8);
    }
    __syncthreads();                   // drains vmcnt(0): staging complete

#pragma unroll
    for (int kk = 0; kk < 64; kk += 32) {
      const int ko = kk + q * 8;       // A/B operand layout: [m|n=lane&15][k=quad*8+j]
      bf16x8 a[2], b[4][2];
#pragma unroll
      for (int mf = 0; mf < 2; ++mf)
        a[mf] = *(const bf16x8*)(As + (wave * 32 + mf * 16 + r) * 64 + ko);
#pragma unroll
      for (int g = 0; g < 4; ++g)
#pragma unroll
        for (int nf = 0; nf < 2; ++nf)
          b[g][nf] = *(const bf16x8*)(Bs + g * 2048 + (nf * 16 + r) * 64 + ko);
#pragma unroll
      for (int g = 0; g < 4; ++g)
#pragma unroll
        for (int mf = 0; mf < 2; ++mf)
#pragma unroll
          for (int nf = 0; nf < 2; ++nf)
            acc[g][mf][nf] = __builtin_amdgcn_mfma_f32_16x16x32_bf16(
                a[mf], b[g][nf], acc[g][mf][nf], 0, 0, 0);
    }
  }

  // Epilogue: D layout col = lane&15 (h), row = quad*4 + reg (m)
#pragma unroll
  for (int nf = 0; nf < 2; ++nf) {
    const int h = h0 + nf * 16 + r;
    const float bi = b0[h], bff = b1[h], bg = b2[h], bo = b3[h], c0 = cxp[h];
#pragma unroll
    for (int mf = 0; mf < 2; ++mf) {
#pragma unroll
      for (int rr = 0; rr < 4; ++rr) {
        const int row = m0 + wave * 32 + mf * 16 + q * 4 + rr;
        const float vi = fast_sigmoid(acc[0][mf][nf][rr] + bi);
        const float vf = fast_sigmoid(acc[1][mf][nf][rr] + bff);
        const float vg = fast_tanh  (acc[2][mf][nf][rr] + bg);
        const float vo = fast_sigmoid(acc[3][mf][nf][rr] + bo);
        const float c  = vf * c0 + vi * vg;   // cx broadcasts over rows
        out[(size_t)row * HDIM + h] = vo * fast_tanh(c);
      }
    }
  }
}

extern "C" void kernel_launch(void* const* d_in, const int* in_sizes, int n_in,
                              void* d_out, int out_size, void* d_ws, size_t ws_size,
                              hipStream_t stream) {
  const float* x   = (const float*)d_in[0];
  const float* Wi  = (const float*)d_in[1];
  const float* bi  = (const float*)d_in[2];
  const float* Wf  = (const float*)d_in[3];
  const float* bf_ = (const float*)d_in[4];
  const float* Wg  = (const float*)d_in[5];
  const float* bg  = (const float*)d_in[6];
  const float* Wo  = (const float*)d_in[7];
  const float* bo  = (const float*)d_in[8];
  const float* cx  = (const float*)d_in[9];

  // Workspace: bf16 x (16 MB) + bf16 W[4] (32 MB) = 48 MB
  unsigned short* xb = (unsigned short*)d_ws;
  unsigned short* wb = xb + (size_t)MDIM * KDIM;

  cvt_x<<<dim3(2048), 256, 0, stream>>>(x, xb, (MDIM * KDIM) / 4);
  cvt_w<<<dim3(1024, 4), 256, 0, stream>>>(Wi, Wf, Wg, Wo, wb);

  lstm_fused<<<dim3(HDIM / 32, MDIM / 128), 256, 0, stream>>>(
      xb, wb, bi, bf_, bg, bo, cx, (float*)d_out);
}

// Round 2
// 342.606 us; speedup vs baseline: 1.0198x; 1.0198x over previous
//
#include <hip/hip_runtime.h>

// Problem dims
#define MDIM 4096
#define KDIM 2048
#define HDIM 2048

using bf16x8  = __attribute__((ext_vector_type(8))) short;           // 8 bf16 = 4 VGPRs
using f32x16  = __attribute__((ext_vector_type(16))) float;          // 32x32 MFMA accumulator
using ushort8 = __attribute__((ext_vector_type(8))) unsigned short;

// ---------- fp32 -> bf16 (RNE) ----------
__device__ __forceinline__ unsigned short f2bf(float f) {
  unsigned u = __float_as_uint(f);
  u += 0x7fffu + ((u >> 16) & 1u);
  return (unsigned short)(u >> 16);
}

// ---------- tiled/fragment-order conversion ----------
// xb_t: [mblk 16][kblk 32][c 2048] chunks of 8 bf16.  c = ((s*8+mgrp)*64+l)
//   src row = mblk*256 + mgrp*32 + (l&31), col = kblk*64 + s*16 + (l>>5)*8
// wb_t: [hblk 64][kblk 32][c 1024] chunks of 8 bf16.  c = ((s*4+gate)*64+l)
//   src h = hblk*32 + (l&31), col = kblk*64 + s*16 + (l>>5)*8
// These slabs are the EXACT LDS image for one block-tile: GEMM staging is a
// linear copy, and every ds_read_b128 is base + lane*16 (conflict-free).
__global__ void cvt_tiled(const float* __restrict__ x,
                          const float* __restrict__ w0, const float* __restrict__ w1,
                          const float* __restrict__ w2, const float* __restrict__ w3,
                          unsigned short* __restrict__ xb, unsigned short* __restrict__ wb) {
  const int t = threadIdx.x;
  if (blockIdx.x < 4096) {                       // ---- x path: 1,048,576 chunks
    int idx  = blockIdx.x * 256 + t;
    int mblk = idx >> 16;
    int kblk = (idx >> 11) & 31;
    int c    = idx & 2047;
    int s = c >> 9, mgrp = (c >> 6) & 7, l = c & 63;
    int row = mblk * 256 + mgrp * 32 + (l & 31);
    int col = kblk * 64 + s * 16 + (l >> 5) * 8;
    const float4* src = (const float4*)(x + (size_t)row * KDIM + col);
    float4 v0 = src[0], v1 = src[1];
    ushort8 o;
    o[0]=f2bf(v0.x); o[1]=f2bf(v0.y); o[2]=f2bf(v0.z); o[3]=f2bf(v0.w);
    o[4]=f2bf(v1.x); o[5]=f2bf(v1.y); o[6]=f2bf(v1.z); o[7]=f2bf(v1.w);
    *(ushort8*)(xb + (size_t)idx * 8) = o;
  } else {                                        // ---- W path: 2,097,152 chunks
    int idx  = (blockIdx.x - 4096) * 256 + t;
    int hblk = idx >> 15;
    int kblk = (idx >> 10) & 31;
    int c    = idx & 1023;
    int s = c >> 8, gate = (c >> 6) & 3, l = c & 63;
    const float* src = (gate == 0) ? w0 : (gate == 1) ? w1 : (gate == 2) ? w2 : w3;
    int h   = hblk * 32 + (l & 31);
    int col = kblk * 64 + s * 16 + (l >> 5) * 8;
    const float4* sp = (const float4*)(src + (size_t)h * KDIM + col);
    float4 v0 = sp[0], v1 = sp[1];
    ushort8 o;
    o[0]=f2bf(v0.x); o[1]=f2bf(v0.y); o[2]=f2bf(v0.z); o[3]=f2bf(v0.w);
    o[4]=f2bf(v1.x); o[5]=f2bf(v1.y); o[6]=f2bf(v1.z); o[7]=f2bf(v1.w);
    *(ushort8*)(wb + (size_t)idx * 8) = o;
  }
}

// ---------- async global -> LDS (16B per lane) ----------
__device__ __forceinline__ void g2l16(const unsigned short* g, unsigned short* l) {
  __builtin_amdgcn_global_load_lds(
      (const __attribute__((address_space(1))) void*)g,
      (__attribute__((address_space(3))) void*)l, 16, 0, 0);
}

// ---------- fast activations (tolerance 1.19e-2) ----------
__device__ __forceinline__ float fast_sigmoid(float x) {
  return __builtin_amdgcn_rcpf(1.f + __expf(-x));
}
__device__ __forceinline__ float fast_tanh(float x) {
  x = fminf(15.f, fmaxf(-15.f, x));
  float e = __expf(2.f * x);
  return (e - 1.f) * __builtin_amdgcn_rcpf(e + 1.f);
}

// ---------- fused 4-gate GEMM + LSTM epilogue ----------
// Block: 256 threads = 4 waves. Block tile 256 M x (4 gates x 32 h), BK=64.
// Wave w: rows [w*64, w*64+64), all 128 n. 32x32x16 MFMA:
//   A: m = lane&31, k = (lane>>5)*8 + j  |  B: n(h) = lane&31, same k
//   D: col(h) = lane&31, row(m) = (reg&3) + 8*(reg>>2) + 4*(lane>>5)
// acc[gate][mf] -> all 4 gates of (m,h) in one lane: epilogue needs no x-lane.
__global__ __launch_bounds__(256) void lstm_fused(
    const unsigned short* __restrict__ xb,   // tiled, see cvt
    const unsigned short* __restrict__ wb,   // tiled
    const float* __restrict__ b0, const float* __restrict__ b1,
    const float* __restrict__ b2, const float* __restrict__ b3,
    const float* __restrict__ cxp,           // [H]
    float* __restrict__ out)                 // [M][H] fp32
{
  __shared__ __align__(16) unsigned short As[16384];   // 32 KB, frag-order
  __shared__ __align__(16) unsigned short Bs[8192];    // 16 KB, frag-order

  const int t    = threadIdx.x;
  const int lane = t & 63;
  const int wave = t >> 6;

  const int m0 = blockIdx.y * 256;
  const int h0 = blockIdx.x * 32;

  f32x16 acc[4][2] = {};    // [gate][mf]

  const unsigned short* aptr = xb + (size_t)blockIdx.y * (32 * 16384);
  const unsigned short* bptr = wb + (size_t)blockIdx.x * (32 * 8192);

  for (int kblk = 0; kblk < 32; ++kblk) {
    __syncthreads();                       // previous tile's reads done
#pragma unroll
    for (int c = 0; c < 8; ++c) {          // A: 32 KB = 8 x 256 lanes x 16 B
      int idx = c * 256 + t;
      g2l16(aptr + (size_t)idx * 8, As + idx * 8);
    }
#pragma unroll
    for (int c = 0; c < 4; ++c) {          // B: 16 KB
      int idx = c * 256 + t;
      g2l16(bptr + (size_t)idx * 8, Bs + idx * 8);
    }
    aptr += 16384; bptr += 8192;
    __syncthreads();                       // staging complete (vmcnt drain)

#pragma unroll
    for (int s = 0; s < 4; ++s) {          // K = 4 x 16
      bf16x8 af[2], bfr[4];
#pragma unroll
      for (int mf = 0; mf < 2; ++mf)
        af[mf] = *(const bf16x8*)(As + ((s * 8 + wave * 2 + mf) * 64 + lane) * 8);
#pragma unroll
      for (int g = 0; g < 4; ++g)
        bfr[g] = *(const bf16x8*)(Bs + ((s * 4 + g) * 64 + lane) * 8);
#pragma unroll
      for (int g = 0; g < 4; ++g)
#pragma unroll
        for (int mf = 0; mf < 2; ++mf)
          acc[g][mf] = __builtin_amdgcn_mfma_f32_32x32x16_bf16(
              af[mf], bfr[g], acc[g][mf], 0, 0, 0);
    }
  }

  // ---- epilogue ----
  const int hcol = h0 + (lane & 31);
  const float bi = b0[hcol], bff = b1[hcol], bgv = b2[hcol], bov = b3[hcol];
  const float c0 = cxp[hcol];
  const int rbase = 4 * (lane >> 5);
#pragma unroll
  for (int mf = 0; mf < 2; ++mf) {
    const int mbase = m0 + (wave * 2 + mf) * 32 + rbase;
#pragma unroll
    for (int rr = 0; rr < 16; ++rr) {
      const int m = mbase + (rr & 3) + 8 * (rr >> 2);
      const float vi = fast_sigmoid(acc[0][mf][rr] + bi);
      const float vf = fast_sigmoid(acc[1][mf][rr] + bff);
      const float vg = fast_tanh  (acc[2][mf][rr] + bgv);
      const float vo = fast_sigmoid(acc[3][mf][rr] + bov);
      const float c  = vf * c0 + vi * vg;
      out[(size_t)m * HDIM + hcol] = vo * fast_tanh(c);
    }
  }
}

extern "C" void kernel_launch(void* const* d_in, const int* in_sizes, int n_in,
                              void* d_out, int out_size, void* d_ws, size_t ws_size,
                              hipStream_t stream) {
  const float* x   = (const float*)d_in[0];
  const float* Wi  = (const float*)d_in[1];
  const float* bi  = (const float*)d_in[2];
  const float* Wf  = (const float*)d_in[3];
  const float* bf_ = (const float*)d_in[4];
  const float* Wg  = (const float*)d_in[5];
  const float* bg  = (const float*)d_in[6];
  const float* Wo  = (const float*)d_in[7];
  const float* bo  = (const float*)d_in[8];
  const float* cx  = (const float*)d_in[9];

  unsigned short* xb = (unsigned short*)d_ws;                 // 16 MB
  unsigned short* wb = xb + (size_t)MDIM * KDIM;              // 32 MB

  cvt_tiled<<<dim3(4096 + 8192), 256, 0, stream>>>(x, Wi, Wf, Wg, Wo, xb, wb);

  lstm_fused<<<dim3(HDIM / 32, MDIM / 256), 256, 0, stream>>>(
      xb, wb, bi, bf_, bg, bo, cx, (float*)d_out);
}